// Round 1
// baseline (293.936 us; speedup 1.0000x reference)
//
#include <hip/hip_runtime.h>
#include <hip/hip_bf16.h>
#include <stdint.h>

// Problem constants: B=2, L=512, D=1024, INNER=32, PAIR=128
// out[b,i,j,p] = sum_e q[b,j,e]*(k[b,i,e]*Wp[p,e] + Wd[p,e]) + (b_o[p] - sum_e k[b,i,e]*Wd[p,e])
//   => per (b,i): GEMM  Q(512x32) * G(32x128) + c0[p],  done with mfma_f32_16x16x32_bf16.

typedef __attribute__((ext_vector_type(8))) short short8;
typedef __attribute__((ext_vector_type(4))) float floatx4;

__device__ __forceinline__ unsigned short f2bf(float f) {
    union { float f; unsigned int u; } v; v.f = f;
    return (unsigned short)((v.u + 0x7FFFu + ((v.u >> 16) & 1u)) >> 16); // RNE
}

// ---------------- k0: transpose weights ----------------
// Wt[d][o]  = W_proj[o][d]   (1024 x 64)
// Wot[e][p] = W_o[p][e]      (32 x 128)   e < 32   (prod half)
// Wdt[e][p] = W_o[p][32+e]   (32 x 128)            (diff half)
__global__ __launch_bounds__(256) void k0_transpose(
    const float* __restrict__ Wproj, const float* __restrict__ Wo,
    float* __restrict__ Wt, float* __restrict__ Wot, float* __restrict__ Wdt)
{
    int g = blockIdx.x * 256 + threadIdx.x;   // grid covers 65536 + 8192
    if (g < 65536) {
        int o = g >> 10, d = g & 1023;
        Wt[d * 64 + o] = Wproj[g];
    } else {
        int h = g - 65536;          // 0..8191
        int p = h & 127, e = h >> 7; // e in [0,64)
        float v = Wo[p * 64 + e];
        if (e < 32) Wot[e * 128 + p] = v;
        else        Wdt[(e - 32) * 128 + p] = v;
    }
}

// ---------------- k1: LayerNorm + projection + c0 ----------------
// 256 blocks x 256 threads, 4 rows per block (row = b*512 + l, 1024 rows total)
__global__ __launch_bounds__(256) void k1_ln_proj(
    const float* __restrict__ x, const float* __restrict__ gamma, const float* __restrict__ beta,
    const float* __restrict__ Wt, const float* __restrict__ b_proj,
    const float* __restrict__ Wdt, const float* __restrict__ b_o,
    unsigned short* __restrict__ Qbf, float* __restrict__ Kf, float* __restrict__ C0)
{
    __shared__ float s_sh[4][1024];     // normalized rows
    __shared__ float part[4][64][5];    // projection partials (+1-ish pad on chunk dim)
    __shared__ float k_sh[4][32];

    const int t = threadIdx.x;
    const int w = t >> 6;        // wave id = local row for LN phase
    const int lane = t & 63;
    const int row = blockIdx.x * 4 + w;

    // --- LayerNorm of this wave's row ---
    const float* xr = x + (size_t)row * 1024;
    floatx4 xv[4];
    float sum = 0.f, sq = 0.f;
#pragma unroll
    for (int c = 0; c < 4; ++c) {
        xv[c] = *(const floatx4*)(xr + (c * 64 + lane) * 4);
        sum += xv[c].x + xv[c].y + xv[c].z + xv[c].w;
        sq  += xv[c].x * xv[c].x + xv[c].y * xv[c].y + xv[c].z * xv[c].z + xv[c].w * xv[c].w;
    }
#pragma unroll
    for (int m = 1; m < 64; m <<= 1) {
        sum += __shfl_xor(sum, m, 64);
        sq  += __shfl_xor(sq,  m, 64);
    }
    const float mu   = sum * (1.f / 1024.f);
    const float var  = sq * (1.f / 1024.f) - mu * mu;
    const float rsig = rsqrtf(var + 1e-5f);
#pragma unroll
    for (int c = 0; c < 4; ++c) {
        int d = (c * 64 + lane) * 4;
        floatx4 g4 = *(const floatx4*)(gamma + d);
        floatx4 b4 = *(const floatx4*)(beta + d);
        floatx4 s4;
        s4.x = (xv[c].x - mu) * rsig * g4.x + b4.x;
        s4.y = (xv[c].y - mu) * rsig * g4.y + b4.y;
        s4.z = (xv[c].z - mu) * rsig * g4.z + b4.z;
        s4.w = (xv[c].w - mu) * rsig * g4.w + b4.w;
        *(floatx4*)(&s_sh[w][d]) = s4;
    }
    __syncthreads();

    // --- projection: output o = t&63, d-chunk ch = t>>6; W reads coalesced via Wt ---
    {
        const int o = t & 63;
        const int ch = t >> 6;
        float a0 = 0.f, a1 = 0.f, a2 = 0.f, a3 = 0.f;
        const float* wp = Wt + (size_t)ch * 256 * 64 + o;
#pragma unroll 4
        for (int d = 0; d < 256; ++d) {
            float wv = wp[(size_t)d * 64];
            int dd = ch * 256 + d;
            a0 += s_sh[0][dd] * wv;
            a1 += s_sh[1][dd] * wv;
            a2 += s_sh[2][dd] * wv;
            a3 += s_sh[3][dd] * wv;
        }
        part[0][o][ch] = a0; part[1][o][ch] = a1;
        part[2][o][ch] = a2; part[3][o][ch] = a3;
    }
    __syncthreads();

    // --- combine partials: thread t -> (r = t>>6, o = t&63) ---
    {
        const int r = t >> 6, oo = t & 63;
        float v = part[r][oo][0] + part[r][oo][1] + part[r][oo][2] + part[r][oo][3] + b_proj[oo];
        const int rowr = blockIdx.x * 4 + r;
        if (oo < 32) {
            Qbf[rowr * 32 + oo] = f2bf(v);     // q in bf16 (MFMA A operand)
        } else {
            Kf[rowr * 32 + (oo - 32)] = v;     // k in fp32
            k_sh[r][oo - 32] = v;
        }
    }
    __syncthreads();

    // --- c0[row][p] = b_o[p] - sum_e k[row][e]*Wd[p][e]  (exact fp32) ---
    {
        const int p = t & 127;
        const int r0 = t >> 7;  // 0 or 1
#pragma unroll
        for (int rr = 0; rr < 2; ++rr) {
            const int r = r0 * 2 + rr;
            float a = 0.f;
#pragma unroll 8
            for (int e = 0; e < 32; ++e) a += k_sh[r][e] * Wdt[e * 128 + p];
            C0[(size_t)(blockIdx.x * 4 + r) * 128 + p] = b_o[p] - a;
        }
    }
}

// ---------------- k2: the pairwise GEMM, 1 block per (b,i) ----------------
// 1024 blocks x 256 threads (4 waves). Per block: build G(32x128) bf16 in LDS,
// keep 8 B-fragments + 8 c0 values resident, sweep j: 8 j-tiles per wave.
__global__ __launch_bounds__(256) void k2_pair(
    const unsigned short* __restrict__ Qbf, const float* __restrict__ Kf,
    const float* __restrict__ C0, const float* __restrict__ Wot, const float* __restrict__ Wdt,
    float* __restrict__ out)
{
    __shared__ unsigned short G[32 * 136];  // rows padded 128->136 to spread LDS banks
    __shared__ float c0s[128];
    __shared__ float ksh[32];

    const int t  = threadIdx.x;
    const int bi = blockIdx.x;        // b*512 + i
    const int b  = bi >> 9;

    if (t < 32)  ksh[t]  = Kf[(size_t)bi * 32 + t];
    if (t < 128) c0s[t] = C0[(size_t)bi * 128 + t];
    __syncthreads();

    // G[e][p] = bf16( k_i[e]*Wp[p][e] + Wd[p][e] ), coalesced via Wot/Wdt
#pragma unroll
    for (int it = 0; it < 16; ++it) {
        int idx = it * 256 + t;       // 0..4095
        int e = idx >> 7, p = idx & 127;
        float gv = ksh[e] * Wot[idx] + Wdt[idx];
        G[e * 136 + p] = f2bf(gv);
    }
    __syncthreads();

    const int wave = t >> 6, lane = t & 63;
    const int col = lane & 15, quad = lane >> 4;

    // B fragments: B[k][n] with k = quad*8 + u, n = pt*16 + col   (resident, 32 VGPRs)
    short8 bfrag[8];
#pragma unroll
    for (int pt = 0; pt < 8; ++pt) {
        short8 f;
#pragma unroll
        for (int u = 0; u < 8; ++u)
            f[u] = (short)G[(quad * 8 + u) * 136 + pt * 16 + col];
        bfrag[pt] = f;
    }
    float cv[8];
#pragma unroll
    for (int pt = 0; pt < 8; ++pt) cv[pt] = c0s[pt * 16 + col];

    const size_t outbase = (size_t)bi * (512 * 128);

    for (int l = 0; l < 8; ++l) {
        const int jt = wave * 8 + l;
        const int j0 = jt * 16;
        // A fragment: A[m][k], m = j0+col (row of Qbf), k = quad*8..quad*8+7 -> one 16B load
        const short8 afrag =
            *(const short8*)(Qbf + ((size_t)b * 512 + j0 + col) * 32 + quad * 8);
        floatx4 acc[8];
#pragma unroll
        for (int pt = 0; pt < 8; ++pt) {
            floatx4 c;
            c.x = cv[pt]; c.y = cv[pt]; c.z = cv[pt]; c.w = cv[pt];
            acc[pt] = __builtin_amdgcn_mfma_f32_16x16x32_bf16(afrag, bfrag[pt], c, 0, 0, 0);
        }
        // C/D layout: row = quad*4 + r, col = lane&15
        float* op = out + outbase + (size_t)(j0 + quad * 4) * 128 + col;
#pragma unroll
        for (int pt = 0; pt < 8; ++pt) {
#pragma unroll
            for (int r = 0; r < 4; ++r) {
                op[r * 128 + pt * 16] = acc[pt][r];
            }
        }
    }
}

extern "C" void kernel_launch(void* const* d_in, const int* in_sizes, int n_in,
                              void* d_out, int out_size, void* d_ws, size_t ws_size,
                              hipStream_t stream) {
    const float* x     = (const float*)d_in[0];  // (2,512,1024)
    const float* gamma = (const float*)d_in[1];  // (1024)
    const float* beta  = (const float*)d_in[2];  // (1024)
    const float* Wproj = (const float*)d_in[3];  // (64,1024)
    const float* bproj = (const float*)d_in[4];  // (64)
    const float* Wo    = (const float*)d_in[5];  // (128,64)
    const float* bo    = (const float*)d_in[6];  // (128)
    float* out = (float*)d_out;                  // (2,512,512,128) fp32

    float* ws = (float*)d_ws;
    float* Wt  = ws;                    // 65536 floats (1024x64)
    float* Wot = ws + 65536;            // 4096 floats  (32x128)
    float* Wdt = ws + 69632;            // 4096 floats  (32x128)
    float* Kf  = ws + 73728;            // 32768 floats (1024x32)
    float* C0  = ws + 106496;           // 131072 floats (1024x128)
    unsigned short* Qbf = (unsigned short*)(ws + 237568); // 32768 ushorts (1024x32)
    // total ws use: ~1.02 MB

    hipLaunchKernelGGL(k0_transpose, dim3(288), dim3(256), 0, stream,
                       Wproj, Wo, Wt, Wot, Wdt);
    hipLaunchKernelGGL(k1_ln_proj, dim3(256), dim3(256), 0, stream,
                       x, gamma, beta, Wt, bproj, Wdt, bo, Qbf, Kf, C0);
    hipLaunchKernelGGL(k2_pair, dim3(1024), dim3(256), 0, stream,
                       Qbf, Kf, C0, Wot, Wdt, out);
}

// Round 2
// 284.791 us; speedup vs baseline: 1.0321x; 1.0321x over previous
//
#include <hip/hip_runtime.h>
#include <hip/hip_bf16.h>
#include <stdint.h>

// Problem constants: B=2, L=512, D=1024, INNER=32, PAIR=128
// out[b,i,j,p] = sum_e q[b,j,e]*(k[b,i,e]*Wp[p,e] + Wd[p,e]) + (b_o[p] - sum_e k[b,i,e]*Wd[p,e])
//   => per (b,i): GEMM  Q(512x32) * G_i(32x128) + c0_i[p], via mfma_f32_16x16x32_bf16.

typedef __attribute__((ext_vector_type(8))) short short8;
typedef __attribute__((ext_vector_type(4))) float floatx4;

__device__ __forceinline__ unsigned short f2bf(float f) {
    union { float f; unsigned int u; } v; v.f = f;
    return (unsigned short)((v.u + 0x7FFFu + ((v.u >> 16) & 1u)) >> 16); // RNE
}

__device__ __forceinline__ floatx4 fmadd4(float s, floatx4 w, floatx4 a) {
    a.x += s * w.x; a.y += s * w.y; a.z += s * w.z; a.w += s * w.w; return a;
}

// ---------------- k0: transpose weights ----------------
// Wt[d][o]  = W_proj[o][d]   (1024 x 64)
// Wot[e][p] = W_o[p][e]      (32 x 128)  prod half
// Wdt[e][p] = W_o[p][32+e]   (32 x 128)  diff half
__global__ __launch_bounds__(256) void k0_transpose(
    const float* __restrict__ Wproj, const float* __restrict__ Wo,
    float* __restrict__ Wt, float* __restrict__ Wot, float* __restrict__ Wdt)
{
    int g = blockIdx.x * 256 + threadIdx.x;
    if (g < 65536) {
        int o = g >> 10, d = g & 1023;
        Wt[d * 64 + o] = Wproj[g];
    } else {
        int h = g - 65536;           // 0..8191
        int p = h & 127, e = h >> 7; // e in [0,64)
        float v = Wo[p * 64 + e];
        if (e < 32) Wot[e * 128 + p] = v;
        else        Wdt[(e - 32) * 128 + p] = v;
    }
}

// ---------------- k1: LayerNorm + projection + c0 ----------------
// 256 blocks x 256 threads, 4 rows per block. Projection uses float4 Wt loads.
__global__ __launch_bounds__(256) void k1_ln_proj(
    const float* __restrict__ x, const float* __restrict__ gamma, const float* __restrict__ beta,
    const float* __restrict__ Wt, const float* __restrict__ b_proj,
    const float* __restrict__ Wdt, const float* __restrict__ b_o,
    unsigned short* __restrict__ Qbf, float* __restrict__ Kf, float* __restrict__ C0)
{
    __shared__ __attribute__((aligned(16))) float s_sh[4][1024];
    __shared__ __attribute__((aligned(16))) float part[4][16][68];  // [row][chunk][o], o-dim padded
    __shared__ float k_sh[4][32];

    const int t = threadIdx.x;
    const int w = t >> 6;        // wave id = local row for LN phase
    const int lane = t & 63;
    const int row = blockIdx.x * 4 + w;

    // --- LayerNorm of this wave's row ---
    const float* xr = x + (size_t)row * 1024;
    floatx4 xv[4];
    float sum = 0.f, sq = 0.f;
#pragma unroll
    for (int c = 0; c < 4; ++c) {
        xv[c] = *(const floatx4*)(xr + (c * 64 + lane) * 4);
        sum += xv[c].x + xv[c].y + xv[c].z + xv[c].w;
        sq  += xv[c].x * xv[c].x + xv[c].y * xv[c].y + xv[c].z * xv[c].z + xv[c].w * xv[c].w;
    }
#pragma unroll
    for (int m = 1; m < 64; m <<= 1) {
        sum += __shfl_xor(sum, m, 64);
        sq  += __shfl_xor(sq,  m, 64);
    }
    const float mu   = sum * (1.f / 1024.f);
    const float var  = sq * (1.f / 1024.f) - mu * mu;
    const float rsig = rsqrtf(var + 1e-5f);
#pragma unroll
    for (int c = 0; c < 4; ++c) {
        int d = (c * 64 + lane) * 4;
        floatx4 g4 = *(const floatx4*)(gamma + d);
        floatx4 b4 = *(const floatx4*)(beta + d);
        floatx4 s4;
        s4.x = (xv[c].x - mu) * rsig * g4.x + b4.x;
        s4.y = (xv[c].y - mu) * rsig * g4.y + b4.y;
        s4.z = (xv[c].z - mu) * rsig * g4.z + b4.z;
        s4.w = (xv[c].w - mu) * rsig * g4.w + b4.w;
        *(floatx4*)(&s_sh[w][d]) = s4;
    }
    __syncthreads();

    // --- projection: thread t -> outputs 4*(t&15)..+3, d-chunk (t>>4) of 64 ---
    {
        const int o4 = t & 15;
        const int ch = t >> 4;
        const floatx4* Wt4 = (const floatx4*)Wt;
        floatx4 a0 = {0.f, 0.f, 0.f, 0.f}, a1 = a0, a2 = a0, a3 = a0;
        const int dbase = ch * 64;
#pragma unroll 8
        for (int dd = 0; dd < 64; ++dd) {
            const int d = dbase + dd;
            floatx4 w4 = Wt4[d * 16 + o4];   // 16B coalesced, L2-resident
            a0 = fmadd4(s_sh[0][d], w4, a0);
            a1 = fmadd4(s_sh[1][d], w4, a1);
            a2 = fmadd4(s_sh[2][d], w4, a2);
            a3 = fmadd4(s_sh[3][d], w4, a3);
        }
        *(floatx4*)&part[0][ch][o4 * 4] = a0;
        *(floatx4*)&part[1][ch][o4 * 4] = a1;
        *(floatx4*)&part[2][ch][o4 * 4] = a2;
        *(floatx4*)&part[3][ch][o4 * 4] = a3;
    }
    __syncthreads();

    // --- combine partials: thread t -> (r = t>>6, o = t&63) ---
    {
        const int r = t >> 6, oo = t & 63;
        float v = b_proj[oo];
#pragma unroll
        for (int c = 0; c < 16; ++c) v += part[r][c][oo];
        const int rowr = blockIdx.x * 4 + r;
        if (oo < 32) {
            Qbf[rowr * 32 + oo] = f2bf(v);     // q in bf16 (MFMA A operand)
        } else {
            Kf[rowr * 32 + (oo - 32)] = v;     // k in fp32
            k_sh[r][oo - 32] = v;
        }
    }
    __syncthreads();

    // --- c0[row][p] = b_o[p] - sum_e k[row][e]*Wd[p][e]  (exact fp32) ---
    {
        const int p = t & 127;
        const int r0 = t >> 7;  // 0 or 1
#pragma unroll
        for (int rr = 0; rr < 2; ++rr) {
            const int r = r0 * 2 + rr;
            float a = 0.f;
#pragma unroll 8
            for (int e = 0; e < 32; ++e) a += k_sh[r][e] * Wdt[e * 128 + p];
            C0[(size_t)(blockIdx.x * 4 + r) * 128 + p] = b_o[p] - a;
        }
    }
}

// ---------------- k2: pairwise GEMM ----------------
// 2048 blocks x 256 threads: block = (bi, half). Per block: G(32x128) bf16 in LDS,
// 8 resident B-fragments/lane; each wave does 4 j-tiles; epilogue transposes the
// 16x128 fp32 tile through LDS and streams it with nontemporal dwordx4 (1KB/wave/instr).
__global__ __launch_bounds__(256) void k2_pair(
    const unsigned short* __restrict__ Qbf, const float* __restrict__ Kf,
    const float* __restrict__ C0, const float* __restrict__ Wot, const float* __restrict__ Wdt,
    float* __restrict__ out)
{
    __shared__ unsigned short G[32 * 136];                 // rows padded 128->136
    __shared__ __attribute__((aligned(16))) float T[4][16][132]; // per-wave transpose tile
    __shared__ float c0s[128];
    __shared__ float ksh[32];

    const int t    = threadIdx.x;
    const int bi   = blockIdx.x >> 1;   // b*512 + i
    const int half = blockIdx.x & 1;
    const int b    = bi >> 9;

    if (t < 32)  ksh[t] = Kf[(size_t)bi * 32 + t];
    if (t < 128) c0s[t] = C0[(size_t)bi * 128 + t];
    __syncthreads();

    // G[e][p] = bf16( k_i[e]*Wp[p][e] + Wd[p][e] )
#pragma unroll
    for (int it = 0; it < 16; ++it) {
        int idx = it * 256 + t;       // 0..4095
        int e = idx >> 7, p = idx & 127;
        float gv = ksh[e] * Wot[idx] + Wdt[idx];
        G[e * 136 + p] = f2bf(gv);
    }
    __syncthreads();

    const int wave = t >> 6, lane = t & 63;
    const int col = lane & 15, quad = lane >> 4;

    // B fragments: B[k][n], k = quad*8+u, n = pt*16+col (resident)
    short8 bfrag[8];
#pragma unroll
    for (int pt = 0; pt < 8; ++pt) {
        short8 f;
#pragma unroll
        for (int u = 0; u < 8; ++u)
            f[u] = (short)G[(quad * 8 + u) * 136 + pt * 16 + col];
        bfrag[pt] = f;
    }
    float cv[8];
#pragma unroll
    for (int pt = 0; pt < 8; ++pt) cv[pt] = c0s[pt * 16 + col];

    const size_t outbase = (size_t)bi * (512 * 128);
    float (*Tw)[132] = T[wave];

    for (int l = 0; l < 4; ++l) {
        const int jt = half * 16 + wave * 4 + l;
        const int j0 = jt * 16;
        // A fragment: A[m][k], m = j0+col, k = quad*8..+7 -> one 16B load
        const short8 afrag =
            *(const short8*)(Qbf + ((size_t)b * 512 + j0 + col) * 32 + quad * 8);
        floatx4 acc[8];
#pragma unroll
        for (int pt = 0; pt < 8; ++pt) {
            floatx4 c;
            c.x = cv[pt]; c.y = cv[pt]; c.z = cv[pt]; c.w = cv[pt];
            acc[pt] = __builtin_amdgcn_mfma_f32_16x16x32_bf16(afrag, bfrag[pt], c, 0, 0, 0);
        }
        // C/D layout: row = quad*4 + r, col16 = lane&15; col = pt*16 + col16.
        // Transpose through per-wave LDS tile, then stream 1KB nontemporal stores.
#pragma unroll
        for (int pt = 0; pt < 8; ++pt) {
#pragma unroll
            for (int r = 0; r < 4; ++r)
                Tw[quad * 4 + r][pt * 16 + col] = acc[pt][r];
        }
        float* orow = out + outbase + (size_t)j0 * 128;
#pragma unroll
        for (int s = 0; s < 8; ++s) {
            int idx = s * 64 + lane;        // 0..511 -> (row = idx>>5, c4 = idx&31)
            int rr = idx >> 5, c4 = idx & 31;
            floatx4 v = *(const floatx4*)&Tw[rr][c4 * 4];
            __builtin_nontemporal_store(v, (floatx4*)(orow + rr * 128 + c4 * 4));
        }
    }
}

extern "C" void kernel_launch(void* const* d_in, const int* in_sizes, int n_in,
                              void* d_out, int out_size, void* d_ws, size_t ws_size,
                              hipStream_t stream) {
    const float* x     = (const float*)d_in[0];  // (2,512,1024)
    const float* gamma = (const float*)d_in[1];  // (1024)
    const float* beta  = (const float*)d_in[2];  // (1024)
    const float* Wproj = (const float*)d_in[3];  // (64,1024)
    const float* bproj = (const float*)d_in[4];  // (64)
    const float* Wo    = (const float*)d_in[5];  // (128,64)
    const float* bo    = (const float*)d_in[6];  // (128)
    float* out = (float*)d_out;                  // (2,512,512,128) fp32

    float* ws = (float*)d_ws;
    float* Wt  = ws;                    // 65536 floats (1024x64)
    float* Wot = ws + 65536;            // 4096 floats  (32x128)
    float* Wdt = ws + 69632;            // 4096 floats  (32x128)
    float* Kf  = ws + 73728;            // 32768 floats (1024x32)
    float* C0  = ws + 106496;           // 131072 floats (1024x128)
    unsigned short* Qbf = (unsigned short*)(ws + 237568); // 32768 ushorts (1024x32)

    hipLaunchKernelGGL(k0_transpose, dim3(288), dim3(256), 0, stream,
                       Wproj, Wo, Wt, Wot, Wdt);
    hipLaunchKernelGGL(k1_ln_proj, dim3(256), dim3(256), 0, stream,
                       x, gamma, beta, Wt, bproj, Wdt, bo, Qbf, Kf, C0);
    hipLaunchKernelGGL(k2_pair, dim3(2048), dim3(256), 0, stream,
                       Qbf, Kf, C0, Wot, Wdt, out);
}